// Round 2
// baseline (565.450 us; speedup 1.0000x reference)
//
#include <hip/hip_runtime.h>

#define BATCH 4
#define SEQ   4096
#define HID   4096
#define OUTF  4096
#define NA    8
#define RANK  64

typedef __attribute__((ext_vector_type(8))) short  short8;
typedef __attribute__((ext_vector_type(4))) float  f32x4;

// round-half-up fp32 -> bf16 (inputs are finite Gaussians; no NaN handling needed)
__device__ __forceinline__ unsigned short cvt_bf16(float f) {
  return (unsigned short)((__float_as_uint(f) + 0x8000u) >> 16);
}
__device__ __forceinline__ unsigned int pack_bf16_2(float lo, float hi) {
  unsigned int a = __float_as_uint(lo);
  unsigned int b = __float_as_uint(hi);
  return ((a + 0x8000u) >> 16) | ((b + 0x8000u) & 0xFFFF0000u);
}

// ---------------------------------------------------------------------------
// Kernel 0: convert + transpose the small matrices so MFMA fragments are
// K-contiguous 16B loads.
//   Bct[a][r][h] = bf16(B[h][a][r])   (8 x 64 x 4096)
//   Act[a][o][r] = bf16(A[a][r][o])   (8 x 4096 x 64)
// ---------------------------------------------------------------------------
__global__ __launch_bounds__(256) void prep_kernel(
    const float* __restrict__ A, const float* __restrict__ Bm,
    unsigned short* __restrict__ Bct, unsigned short* __restrict__ Act) {
  __shared__ unsigned short lds[64 * 72];
  int bid = blockIdx.x;
  int t   = threadIdx.x;
  int lo  = t & 63;   // fast (coalesced) dim
  int hi4 = t >> 6;   // 0..3
  if (bid < 512) {
    int a  = bid >> 6;
    int h0 = (bid & 63) << 6;
    #pragma unroll
    for (int p = 0; p < 16; ++p) {          // read B[h][a][r], r = lo
      int hl = (p << 2) + hi4;
      float v = Bm[((size_t)(h0 + hl) * NA + a) * RANK + lo];
      lds[lo * 72 + hl] = cvt_bf16(v);      // lds[r][h]
    }
    __syncthreads();
    #pragma unroll
    for (int p = 0; p < 16; ++p) {          // write Bct[a][r][h], h = lo
      int rl = (p << 2) + hi4;
      Bct[((size_t)a * RANK + rl) * HID + h0 + lo] = lds[rl * 72 + lo];
    }
  } else {
    int b2 = bid - 512;
    int a  = b2 >> 6;
    int o0 = (b2 & 63) << 6;
    #pragma unroll
    for (int p = 0; p < 16; ++p) {          // read A[a][r][o], o = lo
      int rl = (p << 2) + hi4;
      float v = A[((size_t)a * RANK + rl) * OUTF + o0 + lo];
      lds[lo * 72 + rl] = cvt_bf16(v);      // lds[o][r]
    }
    __syncthreads();
    #pragma unroll
    for (int p = 0; p < 16; ++p) {          // write Act[a][o][r], r = lo
      int ol = (p << 2) + hi4;
      Act[((size_t)a * OUTF + o0 + ol) * RANK + lo] = lds[ol * 72 + lo];
    }
  }
}

// ---------------------------------------------------------------------------
// Fused kernel: one block = one 16-row s-tile of one batch.
//   phase 1 (sdd): Bx[16][64] = bf16( (x_tile @ B_a) / 64 )   -> LDS only
//   phase 2 (dsd): out_tile[16][4096] = Bx @ A_a              -> f32x4 stores
// Grid: 1024 blocks; batch = bid & 3 so each XCD (bid % 8 round-robin) serves
// exactly one batch -> one adapter's Bct+Act (1 MB) stays L2-resident.
// Block = 4 waves; phase 1 splits K=4096 across waves (1024 each), cross-wave
// reduce through LDS; phase 2 gives each wave a 1024-wide o-range.
// ---------------------------------------------------------------------------
__global__ __launch_bounds__(256) void fused_kernel(
    const float* __restrict__ x, const int* __restrict__ ids,
    const unsigned short* __restrict__ Bct, const unsigned short* __restrict__ Act,
    float* __restrict__ out) {
  __shared__ float red[4 * 16 * 65];          // 16.6 KB cross-wave partials
  __shared__ unsigned short bx[16 * 72];      // Bx tile, bf16, row stride 144B
  int bid   = blockIdx.x;
  int batch = bid & 3;          // XCD-pinned: XCD k -> batch k&3
  int s0    = (bid >> 2) << 4;
  int t     = threadIdx.x;
  int w     = t >> 6;
  int lane  = t & 63;
  int m     = lane & 15;   // A-frag row / D col
  int q     = lane >> 4;   // k offset = q*8 ; D rows q*4+reg
  int a     = ids[batch];

  // ---------------- phase 1: Bx = x_tile @ B_a ----------------
  const float* xrow = x + (size_t)(batch * SEQ + s0 + m) * HID;
  const unsigned short* bbase = Bct + (size_t)a * RANK * HID;

  f32x4 acc[4];
  #pragma unroll
  for (int nt = 0; nt < 4; ++nt) acc[nt] = (f32x4){0.f, 0.f, 0.f, 0.f};

  int kw = w << 10;  // this wave's K range: [w*1024, w*1024+1024)
  for (int it = 0; it < 32; ++it) {
    int k = kw + (it << 5) + (q << 3);
    f32x4 f0 = __builtin_nontemporal_load((const f32x4*)(xrow + k));
    f32x4 f1 = __builtin_nontemporal_load((const f32x4*)(xrow + k + 4));
    union { short8 v; unsigned int u[4]; } af;
    af.u[0] = pack_bf16_2(f0[0], f0[1]);
    af.u[1] = pack_bf16_2(f0[2], f0[3]);
    af.u[2] = pack_bf16_2(f1[0], f1[1]);
    af.u[3] = pack_bf16_2(f1[2], f1[3]);
    #pragma unroll
    for (int nt = 0; nt < 4; ++nt) {
      // B-frag: lane holds B[k = q*8+j][n = nt*16+m]; Bct is [r][h].
      short8 bf = *(const short8*)(bbase + (size_t)(nt * 16 + m) * HID + k);
      acc[nt] = __builtin_amdgcn_mfma_f32_16x16x32_bf16(af.v, bf, acc[nt], 0, 0, 0);
    }
  }

  // C/D layout: col = lane&15 (-> r), row = q*4+reg (-> s)
  #pragma unroll
  for (int nt = 0; nt < 4; ++nt)
    #pragma unroll
    for (int r = 0; r < 4; ++r)
      red[(w * 16 + q * 4 + r) * 65 + nt * 16 + m] = acc[nt][r];
  __syncthreads();

  {
    int row = t >> 4;          // 0..15
    int rb  = (t & 15) << 2;   // 0,4,...,60
    float v0 = red[(0 * 16 + row) * 65 + rb + 0] + red[(1 * 16 + row) * 65 + rb + 0]
             + red[(2 * 16 + row) * 65 + rb + 0] + red[(3 * 16 + row) * 65 + rb + 0];
    float v1 = red[(0 * 16 + row) * 65 + rb + 1] + red[(1 * 16 + row) * 65 + rb + 1]
             + red[(2 * 16 + row) * 65 + rb + 1] + red[(3 * 16 + row) * 65 + rb + 1];
    float v2 = red[(0 * 16 + row) * 65 + rb + 2] + red[(1 * 16 + row) * 65 + rb + 2]
             + red[(2 * 16 + row) * 65 + rb + 2] + red[(3 * 16 + row) * 65 + rb + 2];
    float v3 = red[(0 * 16 + row) * 65 + rb + 3] + red[(1 * 16 + row) * 65 + rb + 3]
             + red[(2 * 16 + row) * 65 + rb + 3] + red[(3 * 16 + row) * 65 + rb + 3];
    // fold the exact *1/64 scale here (power of 2 -> commutes with bf16 rounding)
    const float sc = 1.0f / 64.0f;
    uint2 pk;
    pk.x = pack_bf16_2(v0 * sc, v1 * sc);
    pk.y = pack_bf16_2(v2 * sc, v3 * sc);
    *(uint2*)&bx[row * 72 + rb] = pk;
  }
  __syncthreads();

  // ---------------- phase 2: out_tile = Bx @ A_a ----------------
  // Operand-swapped MFMA: A-frag = Act rows (M = o), B-frag = Bx (N = s).
  // D: col = lane&15 -> s = m ; row = q*4+reg -> o_local, so each lane holds
  // 4 CONTIGUOUS o values -> f32x4 store.
  short8 p0 = *(const short8*)&bx[m * 72 + (q << 3)];        // Bx[s=m][r=q*8..]
  short8 p1 = *(const short8*)&bx[m * 72 + 32 + (q << 3)];   // Bx[s=m][r=32+q*8..]
  const unsigned short* abase = Act + (size_t)a * OUTF * RANK;
  float* orow = out + (size_t)(batch * SEQ + s0 + m) * OUTF;

  for (int i = 0; i < 16; ++i) {
    int o0 = ((w << 4) + i) << 6;      // wave w covers o in [w*1024, w*1024+1024)
    #pragma unroll
    for (int nt = 0; nt < 4; ++nt) {
      const unsigned short* arow = abase + (size_t)(o0 + nt * 16 + m) * RANK;
      short8 b0 = *(const short8*)(arow + (q << 3));
      short8 b1 = *(const short8*)(arow + 32 + (q << 3));
      f32x4 c = (f32x4){0.f, 0.f, 0.f, 0.f};
      c = __builtin_amdgcn_mfma_f32_16x16x32_bf16(b0, p0, c, 0, 0, 0);
      c = __builtin_amdgcn_mfma_f32_16x16x32_bf16(b1, p1, c, 0, 0, 0);
      __builtin_nontemporal_store(c, (f32x4*)(orow + o0 + nt * 16 + (q << 2)));
    }
  }
}

// ---------------------------------------------------------------------------
extern "C" void kernel_launch(void* const* d_in, const int* in_sizes, int n_in,
                              void* d_out, int out_size, void* d_ws, size_t ws_size,
                              hipStream_t stream) {
  const float* x   = (const float*)d_in[0];
  const int*   ids = (const int*)d_in[1];
  const float* A   = (const float*)d_in[2];
  const float* Bm  = (const float*)d_in[3];
  float*       out = (float*)d_out;

  // workspace layout (8 MB total):
  unsigned short* Bct = (unsigned short*)d_ws;                 // 8*64*4096*2 = 4 MB
  unsigned short* Act = Bct + (size_t)NA * RANK * HID;         // 8*4096*64*2 = 4 MB

  prep_kernel <<<1024, 256, 0, stream>>>(A, Bm, Bct, Act);
  fused_kernel<<<1024, 256, 0, stream>>>(x, ids, Bct, Act, out);
}

// Round 3
// 564.172 us; speedup vs baseline: 1.0023x; 1.0023x over previous
//
#include <hip/hip_runtime.h>

#define BATCH 4
#define SEQ   4096
#define HID   4096
#define OUTF  4096
#define NA    8
#define RANK  64

typedef __attribute__((ext_vector_type(8))) short  short8;
typedef __attribute__((ext_vector_type(4))) float  f32x4;

// round-half-up fp32 -> bf16 (inputs are finite Gaussians; no NaN handling needed)
__device__ __forceinline__ unsigned short cvt_bf16(float f) {
  return (unsigned short)((__float_as_uint(f) + 0x8000u) >> 16);
}
__device__ __forceinline__ unsigned int pack_bf16_2(float lo, float hi) {
  unsigned int a = __float_as_uint(lo);
  unsigned int b = __float_as_uint(hi);
  return ((a + 0x8000u) >> 16) | ((b + 0x8000u) & 0xFFFF0000u);
}

// ---------------------------------------------------------------------------
// Kernel 0: convert + transpose the small matrices so MFMA fragments are
// K-contiguous 16B loads.
//   Bct[a][r][h] = bf16(B[h][a][r])   (8 x 64 x 4096)
//   Act[a][o][r] = bf16(A[a][r][o])   (8 x 4096 x 64)
// ---------------------------------------------------------------------------
__global__ __launch_bounds__(256) void prep_kernel(
    const float* __restrict__ A, const float* __restrict__ Bm,
    unsigned short* __restrict__ Bct, unsigned short* __restrict__ Act) {
  __shared__ unsigned short lds[64 * 72];
  int bid = blockIdx.x;
  int t   = threadIdx.x;
  int lo  = t & 63;   // fast (coalesced) dim
  int hi4 = t >> 6;   // 0..3
  if (bid < 512) {
    int a  = bid >> 6;
    int h0 = (bid & 63) << 6;
    #pragma unroll
    for (int p = 0; p < 16; ++p) {          // read B[h][a][r], r = lo
      int hl = (p << 2) + hi4;
      float v = Bm[((size_t)(h0 + hl) * NA + a) * RANK + lo];
      lds[lo * 72 + hl] = cvt_bf16(v);      // lds[r][h]
    }
    __syncthreads();
    #pragma unroll
    for (int p = 0; p < 16; ++p) {          // write Bct[a][r][h], h = lo
      int rl = (p << 2) + hi4;
      Bct[((size_t)a * RANK + rl) * HID + h0 + lo] = lds[rl * 72 + lo];
    }
  } else {
    int b2 = bid - 512;
    int a  = b2 >> 6;
    int o0 = (b2 & 63) << 6;
    #pragma unroll
    for (int p = 0; p < 16; ++p) {          // read A[a][r][o], o = lo
      int rl = (p << 2) + hi4;
      float v = A[((size_t)a * RANK + rl) * OUTF + o0 + lo];
      lds[lo * 72 + rl] = cvt_bf16(v);      // lds[o][r]
    }
    __syncthreads();
    #pragma unroll
    for (int p = 0; p < 16; ++p) {          // write Act[a][o][r], r = lo
      int ol = (p << 2) + hi4;
      Act[((size_t)a * OUTF + o0 + ol) * RANK + lo] = lds[ol * 72 + lo];
    }
  }
}

// ---------------------------------------------------------------------------
// Fused kernel: one block = one 16-row s-tile of one batch. 8 waves / block.
//   phase 1 (sdd): Bx[16][64] = bf16( (x_tile @ B_a) / 64 )   -> LDS only
//                  K=4096 split 8 ways (512/wave, 16 iters), LDS reduce.
//   phase 2 (dsd): out_tile[16][4096] = Bx @ A_a, wave w owns o in
//                  [w*512, w*512+512); operand-swapped MFMA -> f32x4 stores.
// Grid: 1024 blocks; batch = bid & 3 so each XCD (bid % 8 round-robin) serves
// exactly one batch -> one adapter's Bct+Act (1 MB) stays L2-resident.
// LDS 35.6 KB -> 4 blocks/CU x 8 waves = 32 waves/CU (100% occupancy cap);
// __launch_bounds__(512, 8) pins VGPRs <= 64 to actually reach it.
// ---------------------------------------------------------------------------
__global__ __launch_bounds__(512, 8) void fused_kernel(
    const float* __restrict__ x, const int* __restrict__ ids,
    const unsigned short* __restrict__ Bct, const unsigned short* __restrict__ Act,
    float* __restrict__ out) {
  __shared__ float red[8 * 16 * 65];          // 33.3 KB cross-wave partials
  __shared__ unsigned short bx[16 * 72];      // Bx tile, bf16, row stride 144B
  int bid   = blockIdx.x;
  int batch = bid & 3;          // XCD-pinned: XCD k -> batch k&3
  int s0    = (bid >> 2) << 4;
  int t     = threadIdx.x;
  int w     = t >> 6;           // 0..7
  int lane  = t & 63;
  int m     = lane & 15;   // A-frag row / D col
  int q     = lane >> 4;   // k offset = q*8 ; D rows q*4+reg
  int a     = ids[batch];

  // ---------------- phase 1: Bx = x_tile @ B_a ----------------
  const float* xrow = x + (size_t)(batch * SEQ + s0 + m) * HID;
  const unsigned short* bbase = Bct + (size_t)a * RANK * HID;

  f32x4 acc[4];
  #pragma unroll
  for (int nt = 0; nt < 4; ++nt) acc[nt] = (f32x4){0.f, 0.f, 0.f, 0.f};

  int kw = w << 9;  // this wave's K range: [w*512, w*512+512)
  for (int it = 0; it < 16; ++it) {
    int k = kw + (it << 5) + (q << 3);
    f32x4 f0 = __builtin_nontemporal_load((const f32x4*)(xrow + k));
    f32x4 f1 = __builtin_nontemporal_load((const f32x4*)(xrow + k + 4));
    union { short8 v; unsigned int u[4]; } af;
    af.u[0] = pack_bf16_2(f0[0], f0[1]);
    af.u[1] = pack_bf16_2(f0[2], f0[3]);
    af.u[2] = pack_bf16_2(f1[0], f1[1]);
    af.u[3] = pack_bf16_2(f1[2], f1[3]);
    #pragma unroll
    for (int nt = 0; nt < 4; ++nt) {
      // B-frag: lane holds B[k = q*8+j][n = nt*16+m]; Bct is [r][h].
      short8 bf = *(const short8*)(bbase + (size_t)(nt * 16 + m) * HID + k);
      acc[nt] = __builtin_amdgcn_mfma_f32_16x16x32_bf16(af.v, bf, acc[nt], 0, 0, 0);
    }
  }

  // C/D layout: col = lane&15 (-> r), row = q*4+reg (-> s)
  #pragma unroll
  for (int nt = 0; nt < 4; ++nt)
    #pragma unroll
    for (int r = 0; r < 4; ++r)
      red[(w * 16 + q * 4 + r) * 65 + nt * 16 + m] = acc[nt][r];
  __syncthreads();

  if (t < 256) {
    int row = t >> 4;          // 0..15
    int rb  = (t & 15) << 2;   // 0,4,...,60
    float v0 = 0.f, v1 = 0.f, v2 = 0.f, v3 = 0.f;
    #pragma unroll
    for (int ww = 0; ww < 8; ++ww) {
      const float* rr = &red[(ww * 16 + row) * 65 + rb];
      v0 += rr[0]; v1 += rr[1]; v2 += rr[2]; v3 += rr[3];
    }
    // fold the exact *1/64 scale here (power of 2 -> commutes with bf16 rounding)
    const float sc = 1.0f / 64.0f;
    uint2 pk;
    pk.x = pack_bf16_2(v0 * sc, v1 * sc);
    pk.y = pack_bf16_2(v2 * sc, v3 * sc);
    *(uint2*)&bx[row * 72 + rb] = pk;
  }
  __syncthreads();

  // ---------------- phase 2: out_tile = Bx @ A_a ----------------
  // Operand-swapped MFMA: A-frag = Act rows (M = o), B-frag = Bx (N = s).
  // D: col = lane&15 -> s = m ; row = q*4+reg -> o_local, so each lane holds
  // 4 CONTIGUOUS o values -> f32x4 store.
  short8 p0 = *(const short8*)&bx[m * 72 + (q << 3)];        // Bx[s=m][r=q*8..]
  short8 p1 = *(const short8*)&bx[m * 72 + 32 + (q << 3)];   // Bx[s=m][r=32+q*8..]
  const unsigned short* abase = Act + (size_t)a * OUTF * RANK;
  float* orow = out + (size_t)(batch * SEQ + s0 + m) * OUTF;

  for (int i = 0; i < 8; ++i) {
    int o0 = ((w << 3) + i) << 6;      // wave w covers o in [w*512, w*512+512)
    #pragma unroll
    for (int nt = 0; nt < 4; ++nt) {
      const unsigned short* arow = abase + (size_t)(o0 + nt * 16 + m) * RANK;
      short8 b0 = *(const short8*)(arow + (q << 3));
      short8 b1 = *(const short8*)(arow + 32 + (q << 3));
      f32x4 c = (f32x4){0.f, 0.f, 0.f, 0.f};
      c = __builtin_amdgcn_mfma_f32_16x16x32_bf16(b0, p0, c, 0, 0, 0);
      c = __builtin_amdgcn_mfma_f32_16x16x32_bf16(b1, p1, c, 0, 0, 0);
      __builtin_nontemporal_store(c, (f32x4*)(orow + o0 + nt * 16 + (q << 2)));
    }
  }
}

// ---------------------------------------------------------------------------
extern "C" void kernel_launch(void* const* d_in, const int* in_sizes, int n_in,
                              void* d_out, int out_size, void* d_ws, size_t ws_size,
                              hipStream_t stream) {
  const float* x   = (const float*)d_in[0];
  const int*   ids = (const int*)d_in[1];
  const float* A   = (const float*)d_in[2];
  const float* Bm  = (const float*)d_in[3];
  float*       out = (float*)d_out;

  // workspace layout (8 MB total):
  unsigned short* Bct = (unsigned short*)d_ws;                 // 8*64*4096*2 = 4 MB
  unsigned short* Act = Bct + (size_t)NA * RANK * HID;         // 8*4096*64*2 = 4 MB

  prep_kernel <<<1024, 256, 0, stream>>>(A, Bm, Bct, Act);
  fused_kernel<<<1024, 512, 0, stream>>>(x, ids, Bct, Act, out);
}

// Round 4
// 556.580 us; speedup vs baseline: 1.0159x; 1.0136x over previous
//
#include <hip/hip_runtime.h>

#define BATCH 4
#define SEQ   4096
#define HID   4096
#define OUTF  4096
#define NA    8
#define RANK  64

typedef __attribute__((ext_vector_type(8))) short  short8;
typedef __attribute__((ext_vector_type(4))) float  f32x4;

// round-half-up fp32 -> bf16 (inputs are finite Gaussians; no NaN handling needed)
__device__ __forceinline__ unsigned short cvt_bf16(float f) {
  return (unsigned short)((__float_as_uint(f) + 0x8000u) >> 16);
}
__device__ __forceinline__ unsigned int pack_bf16_2(float lo, float hi) {
  unsigned int a = __float_as_uint(lo);
  unsigned int b = __float_as_uint(hi);
  return ((a + 0x8000u) >> 16) | ((b + 0x8000u) & 0xFFFF0000u);
}

// ---------------------------------------------------------------------------
// Kernel 0: convert + transpose the small matrices so MFMA fragments are
// K-contiguous 16B loads.
//   Bct[a][r][h] = bf16(B[h][a][r])   (8 x 64 x 4096)
//   Act[a][o][r] = bf16(A[a][r][o])   (8 x 4096 x 64)
// ---------------------------------------------------------------------------
__global__ __launch_bounds__(256) void prep_kernel(
    const float* __restrict__ A, const float* __restrict__ Bm,
    unsigned short* __restrict__ Bct, unsigned short* __restrict__ Act) {
  __shared__ unsigned short lds[64 * 72];
  int bid = blockIdx.x;
  int t   = threadIdx.x;
  int lo  = t & 63;   // fast (coalesced) dim
  int hi4 = t >> 6;   // 0..3
  if (bid < 512) {
    int a  = bid >> 6;
    int h0 = (bid & 63) << 6;
    #pragma unroll
    for (int p = 0; p < 16; ++p) {          // read B[h][a][r], r = lo
      int hl = (p << 2) + hi4;
      float v = Bm[((size_t)(h0 + hl) * NA + a) * RANK + lo];
      lds[lo * 72 + hl] = cvt_bf16(v);      // lds[r][h]
    }
    __syncthreads();
    #pragma unroll
    for (int p = 0; p < 16; ++p) {          // write Bct[a][r][h], h = lo
      int rl = (p << 2) + hi4;
      Bct[((size_t)a * RANK + rl) * HID + h0 + lo] = lds[rl * 72 + lo];
    }
  } else {
    int b2 = bid - 512;
    int a  = b2 >> 6;
    int o0 = (b2 & 63) << 6;
    #pragma unroll
    for (int p = 0; p < 16; ++p) {          // read A[a][r][o], o = lo
      int rl = (p << 2) + hi4;
      float v = A[((size_t)a * RANK + rl) * OUTF + o0 + lo];
      lds[lo * 72 + rl] = cvt_bf16(v);      // lds[o][r]
    }
    __syncthreads();
    #pragma unroll
    for (int p = 0; p < 16; ++p) {          // write Act[a][o][r], r = lo
      int ol = (p << 2) + hi4;
      Act[((size_t)a * OUTF + o0 + ol) * RANK + lo] = lds[ol * 72 + lo];
    }
  }
}

// ---------------------------------------------------------------------------
// Fused kernel: one block = one 16-row s-tile of one batch. 8 waves / block.
//   phase 1 (sdd): Bx[16][64] = bf16( (x_tile @ B_a) / 64 )   -> LDS only
//                  K=4096 split 8 ways (512/wave, 16 iters), LDS reduce.
//   phase 2 (dsd): out_tile[16][4096] = Bx @ A_a, wave w owns o in
//                  [w*512, w*512+512); operand-swapped MFMA -> f32x4 stores.
// Grid: 1024 blocks; batch = bid & 3 so each XCD (bid % 8 round-robin) serves
// exactly one batch -> one adapter's Bct+Act (1 MB) stays L2-resident.
// Stores are PLAIN (L2 write-allocate): R3 showed nontemporal stores inflate
// WRITE_SIZE 268->320 MB and clamp effective BW at ~2 TB/s (64B no-allocate
// chunks across 16K streams). Let TCC merge full lines and batch evictions.
// ---------------------------------------------------------------------------
__global__ __launch_bounds__(512, 8) void fused_kernel(
    const float* __restrict__ x, const int* __restrict__ ids,
    const unsigned short* __restrict__ Bct, const unsigned short* __restrict__ Act,
    float* __restrict__ out) {
  __shared__ float red[8 * 16 * 65];          // 33.3 KB cross-wave partials
  __shared__ unsigned short bx[16 * 72];      // Bx tile, bf16, row stride 144B
  int bid   = blockIdx.x;
  int batch = bid & 3;          // XCD-pinned: XCD k -> batch k&3
  int s0    = (bid >> 2) << 4;
  int t     = threadIdx.x;
  int w     = t >> 6;           // 0..7
  int lane  = t & 63;
  int m     = lane & 15;   // A-frag row / D col
  int q     = lane >> 4;   // k offset = q*8 ; D rows q*4+reg
  int a     = ids[batch];

  // ---------------- phase 1: Bx = x_tile @ B_a ----------------
  const float* xrow = x + (size_t)(batch * SEQ + s0 + m) * HID;
  const unsigned short* bbase = Bct + (size_t)a * RANK * HID;

  f32x4 acc[4];
  #pragma unroll
  for (int nt = 0; nt < 4; ++nt) acc[nt] = (f32x4){0.f, 0.f, 0.f, 0.f};

  int kw = w << 9;  // this wave's K range: [w*512, w*512+512)
  for (int it = 0; it < 16; ++it) {
    int k = kw + (it << 5) + (q << 3);
    f32x4 f0 = __builtin_nontemporal_load((const f32x4*)(xrow + k));
    f32x4 f1 = __builtin_nontemporal_load((const f32x4*)(xrow + k + 4));
    union { short8 v; unsigned int u[4]; } af;
    af.u[0] = pack_bf16_2(f0[0], f0[1]);
    af.u[1] = pack_bf16_2(f0[2], f0[3]);
    af.u[2] = pack_bf16_2(f1[0], f1[1]);
    af.u[3] = pack_bf16_2(f1[2], f1[3]);
    #pragma unroll
    for (int nt = 0; nt < 4; ++nt) {
      // B-frag: lane holds B[k = q*8+j][n = nt*16+m]; Bct is [r][h].
      short8 bf = *(const short8*)(bbase + (size_t)(nt * 16 + m) * HID + k);
      acc[nt] = __builtin_amdgcn_mfma_f32_16x16x32_bf16(af.v, bf, acc[nt], 0, 0, 0);
    }
  }

  // C/D layout: col = lane&15 (-> r), row = q*4+reg (-> s)
  #pragma unroll
  for (int nt = 0; nt < 4; ++nt)
    #pragma unroll
    for (int r = 0; r < 4; ++r)
      red[(w * 16 + q * 4 + r) * 65 + nt * 16 + m] = acc[nt][r];
  __syncthreads();

  if (t < 256) {
    int row = t >> 4;          // 0..15
    int rb  = (t & 15) << 2;   // 0,4,...,60
    float v0 = 0.f, v1 = 0.f, v2 = 0.f, v3 = 0.f;
    #pragma unroll
    for (int ww = 0; ww < 8; ++ww) {
      const float* rr = &red[(ww * 16 + row) * 65 + rb];
      v0 += rr[0]; v1 += rr[1]; v2 += rr[2]; v3 += rr[3];
    }
    // fold the exact *1/64 scale here (power of 2 -> commutes with bf16 rounding)
    const float sc = 1.0f / 64.0f;
    uint2 pk;
    pk.x = pack_bf16_2(v0 * sc, v1 * sc);
    pk.y = pack_bf16_2(v2 * sc, v3 * sc);
    *(uint2*)&bx[row * 72 + rb] = pk;
  }
  __syncthreads();

  // ---------------- phase 2: out_tile = Bx @ A_a ----------------
  // Operand-swapped MFMA: A-frag = Act rows (M = o), B-frag = Bx (N = s).
  // D: col = lane&15 -> s = m ; row = q*4+reg -> o_local, so each lane holds
  // 4 CONTIGUOUS o values -> f32x4 store (plain, L2-allocating).
  short8 p0 = *(const short8*)&bx[m * 72 + (q << 3)];        // Bx[s=m][r=q*8..]
  short8 p1 = *(const short8*)&bx[m * 72 + 32 + (q << 3)];   // Bx[s=m][r=32+q*8..]
  const unsigned short* abase = Act + (size_t)a * OUTF * RANK;
  float* orow = out + (size_t)(batch * SEQ + s0 + m) * OUTF;

  for (int i = 0; i < 8; ++i) {
    int o0 = ((w << 3) + i) << 6;      // wave w covers o in [w*512, w*512+512)
    #pragma unroll
    for (int nt = 0; nt < 4; ++nt) {
      const unsigned short* arow = abase + (size_t)(o0 + nt * 16 + m) * RANK;
      short8 b0 = *(const short8*)(arow + (q << 3));
      short8 b1 = *(const short8*)(arow + 32 + (q << 3));
      f32x4 c = (f32x4){0.f, 0.f, 0.f, 0.f};
      c = __builtin_amdgcn_mfma_f32_16x16x32_bf16(b0, p0, c, 0, 0, 0);
      c = __builtin_amdgcn_mfma_f32_16x16x32_bf16(b1, p1, c, 0, 0, 0);
      *(f32x4*)(orow + o0 + nt * 16 + (q << 2)) = c;
    }
  }
}

// ---------------------------------------------------------------------------
extern "C" void kernel_launch(void* const* d_in, const int* in_sizes, int n_in,
                              void* d_out, int out_size, void* d_ws, size_t ws_size,
                              hipStream_t stream) {
  const float* x   = (const float*)d_in[0];
  const int*   ids = (const int*)d_in[1];
  const float* A   = (const float*)d_in[2];
  const float* Bm  = (const float*)d_in[3];
  float*       out = (float*)d_out;

  // workspace layout (8 MB total):
  unsigned short* Bct = (unsigned short*)d_ws;                 // 8*64*4096*2 = 4 MB
  unsigned short* Act = Bct + (size_t)NA * RANK * HID;         // 8*4096*64*2 = 4 MB

  prep_kernel <<<1024, 256, 0, stream>>>(A, Bm, Bct, Act);
  fused_kernel<<<1024, 512, 0, stream>>>(x, ids, Bct, Act, out);
}